// Round 1
// baseline (143.034 us; speedup 1.0000x reference)
//
#include <hip/hip_runtime.h>
#include <hip/hip_bf16.h>

typedef float f32x4 __attribute__((ext_vector_type(4)));
typedef short s16x8 __attribute__((ext_vector_type(8)));

#define D_DIM 4096
#define N_COLS 384
#define NT 24            // 16-wide col tiles
#define BM 32
#define NBLK 256         // 8192 / BM
#define KITERS 64        // 4096 / 64
#define DSTRIDE 388      // Dmat padded stride (bank spread)

__device__ __forceinline__ unsigned short f2bf(float f) {
    unsigned u = __float_as_uint(f);
    u += 0x7fffu + ((u >> 16) & 1u);   // RNE
    return (unsigned short)(u >> 16);
}

__global__ __launch_bounds__(64) void reg_init_kernel(const float* __restrict__ C,
                                                      const float* __restrict__ Csin,
                                                      float* __restrict__ reg_out) {
    if (threadIdx.x == 0)
        reg_out[0] = 0.05f * (fabsf(C[0]) + fabsf(C[1]) + fabsf(C[2]) + fabsf(Csin[0]));
}

// Build W [4096 x 384] bf16 in MFMA B-fragment-packed layout:
// element (k, n): chunk = (k>>5)*NT + (n>>4); lane = (((k&31)>>3)<<4) | (n&15); j = k&7
// address = (chunk*64 + lane)*8 + j. One wave builds one 1KB chunk.
// Also accumulates REG_W * sum|U|/size into reg_out (each U element appears exactly once).
__global__ __launch_bounds__(64) void build_w_kernel(const float* __restrict__ U1,
                                                     const float* __restrict__ U2,
                                                     const float* __restrict__ U3,
                                                     unsigned short* __restrict__ W,
                                                     float* __restrict__ reg_out) {
    const int ks = blockIdx.x / NT;
    const int ct = blockIdx.x % NT;
    const int l  = threadIdx.x;
    const int n  = ct * 16 + (l & 15);
    const int kb = ks * 32 + ((l >> 4) << 3);

    const float* src;
    float scale;
    if (n < 64)       { src = U1 + n;                  scale = 0.01f / 262144.f; }
    else if (n < 128) { src = U2 + (n - 64);           scale = 0.01f / 524288.f; }
    else if (n < 192) { src = U2 + 262144 + (n - 128); scale = 0.01f / 524288.f; }
    else if (n < 256) { src = U3 + (n - 192);          scale = 0.01f / 786432.f; }
    else if (n < 320) { src = U3 + 262144 + (n - 256); scale = 0.01f / 786432.f; }
    else              { src = U3 + 524288 + (n - 320); scale = 0.01f / 786432.f; }

    unsigned short h[8];
    float sabs = 0.f;
#pragma unroll
    for (int j = 0; j < 8; ++j) {
        float u = src[(size_t)(kb + j) * 64];
        sabs += fabsf(u);
        h[j] = f2bf(u);
    }
    uint4 pk;
    pk.x = (unsigned)h[0] | ((unsigned)h[1] << 16);
    pk.y = (unsigned)h[2] | ((unsigned)h[3] << 16);
    pk.z = (unsigned)h[4] | ((unsigned)h[5] << 16);
    pk.w = (unsigned)h[6] | ((unsigned)h[7] << 16);
    *(uint4*)(W + ((size_t)blockIdx.x * 64 + l) * 8) = pk;

    sabs *= scale;
#pragma unroll
    for (int off = 32; off >= 1; off >>= 1)
        sabs += __shfl_xor(sabs, off, 64);
    if (l == 0) atomicAdd(reg_out, sabs);
}

// Fused: GEMM (bf16 MFMA) + row sin-sum + nonlinear combine.
// 256 blocks x 512 threads; block owns 32 rows; 8 waves = 2 row-tiles x 3 col-tiles each.
__global__ __launch_bounds__(512) void poly_main_kernel(const float* __restrict__ X,
                                                        const unsigned short* __restrict__ W,
                                                        const float* __restrict__ C,
                                                        const float* __restrict__ beta,
                                                        const float* __restrict__ Csin,
                                                        float* __restrict__ out) {
    __shared__ short Atile[2][2][2][64 * 8];   // [buf][ks][rt][lane*8]  (frag-packed), 8 KB
    __shared__ float Dmat[BM][DSTRIDE];        // 48.5 KB
    __shared__ float sinrow[BM];

    const int t    = threadIdx.x;
    const int lane = t & 63;
    const int wv   = t >> 6;
    const int row0 = blockIdx.x * BM;

    // staging assignment: thread -> (row, 4 consecutive k)
    const int srow = t >> 4;              // 0..31
    const int sc4  = (t & 15) << 2;       // 0..60 (k within BK=64)
    const int rt_s = srow >> 4;
    const int ks_s = sc4 >> 5;
    const int lane_a = (((sc4 & 31) >> 3) << 4) | (srow & 15);
    const int j0 = sc4 & 7;               // 0 or 4

    const float* xp = X + (size_t)(row0 + srow) * D_DIM + sc4;
    short* awr = &Atile[0][ks_s][rt_s][lane_a * 8 + j0];
    const int bufoff = 2 * 2 * 64 * 8;    // shorts per buffer

    const s16x8* __restrict__ Wf = (const s16x8*)W;
    const int ct0 = wv * 3;

    f32x4 acc[2][3];
#pragma unroll
    for (int r = 0; r < 2; ++r)
#pragma unroll
        for (int c = 0; c < 3; ++c)
            acc[r][c] = (f32x4){0.f, 0.f, 0.f, 0.f};

    float sinacc = 0.f;

    for (int it = 0; it < KITERS; ++it) {
        // stage X tile: load f32x4, sin-accumulate, convert, frag-packed LDS write
        f32x4 xv = *(const f32x4*)(xp + it * 64);
        sinacc += __sinf(xv.x) + __sinf(xv.y) + __sinf(xv.z) + __sinf(xv.w);
        short4 hb;
        hb.x = (short)f2bf(xv.x);
        hb.y = (short)f2bf(xv.y);
        hb.z = (short)f2bf(xv.z);
        hb.w = (short)f2bf(xv.w);
        *(short4*)(awr + (it & 1) * bufoff) = hb;
        __syncthreads();   // single barrier per iter (double-buffered A tile)

        const short* abase = &Atile[it & 1][0][0][0];
#pragma unroll
        for (int ks = 0; ks < 2; ++ks) {
            s16x8 a0 = *(const s16x8*)(abase + (ks * 2 + 0) * 512 + lane * 8);
            s16x8 a1 = *(const s16x8*)(abase + (ks * 2 + 1) * 512 + lane * 8);
            const size_t wbase = ((size_t)(it * 2 + ks) * NT + ct0) * 64 + lane;
#pragma unroll
            for (int c = 0; c < 3; ++c) {
                s16x8 b = Wf[wbase + (size_t)c * 64];   // global, L2-resident, coalesced
                acc[0][c] = __builtin_amdgcn_mfma_f32_16x16x32_bf16(a0, b, acc[0][c], 0, 0, 0);
                acc[1][c] = __builtin_amdgcn_mfma_f32_16x16x32_bf16(a1, b, acc[1][c], 0, 0, 0);
            }
        }
    }

    // ---- epilogue ----
    // dump accumulators: D row = rt*16 + (lane>>4)*4 + i, col = ct*16 + (lane&15)
    const int lr4 = (lane >> 4) << 2;
    const int lc  = lane & 15;
#pragma unroll
    for (int r = 0; r < 2; ++r)
#pragma unroll
        for (int c = 0; c < 3; ++c) {
            const int col = (ct0 + c) * 16 + lc;
#pragma unroll
            for (int i = 0; i < 4; ++i)
                Dmat[r * 16 + lr4 + i][col] = acc[r][c][i];
        }

    // row sin reduction (16 threads per row, consecutive lanes)
#pragma unroll
    for (int off = 1; off < 16; off <<= 1)
        sinacc += __shfl_xor(sinacc, off, 16);
    if ((t & 15) == 0) sinrow[srow] = sinacc;
    __syncthreads();

    // combine: 16 threads per row
    const int crow = t >> 4;
    const int cc   = t & 15;
    float t1 = 0.f, t2 = 0.f, t3 = 0.f;
#pragma unroll
    for (int rr = 0; rr < 64; rr += 16) {
        const int r = rr + cc;
        t1 += Dmat[crow][r];
        t2 += Dmat[crow][64 + r]  * Dmat[crow][128 + r];
        t3 += Dmat[crow][192 + r] * Dmat[crow][256 + r] * Dmat[crow][320 + r];
    }
#pragma unroll
    for (int off = 1; off < 16; off <<= 1) {
        t1 += __shfl_xor(t1, off, 16);
        t2 += __shfl_xor(t2, off, 16);
        t3 += __shfl_xor(t3, off, 16);
    }
    if (cc == 0)
        out[row0 + crow] = beta[0] + C[0] * t1 + C[1] * t2 + C[2] * t3
                         + Csin[0] * sinrow[crow];
}

extern "C" void kernel_launch(void* const* d_in, const int* in_sizes, int n_in,
                              void* d_out, int out_size, void* d_ws, size_t ws_size,
                              hipStream_t stream) {
    const float* X   = (const float*)d_in[0];
    const float* U1  = (const float*)d_in[1];
    const float* U2  = (const float*)d_in[2];
    const float* U3  = (const float*)d_in[3];
    const float* Cc  = (const float*)d_in[4];
    const float* bet = (const float*)d_in[5];
    const float* Cs  = (const float*)d_in[6];
    float* out = (float*)d_out;
    unsigned short* W = (unsigned short*)d_ws;   // 3 MiB bf16, frag-packed

    reg_init_kernel<<<1, 64, 0, stream>>>(Cc, Cs, out + 8192);
    build_w_kernel<<<128 * NT, 64, 0, stream>>>(U1, U2, U3, W, out + 8192);
    poly_main_kernel<<<NBLK, 512, 0, stream>>>(X, W, Cc, bet, Cs, out);
}

// Round 2
// 130.136 us; speedup vs baseline: 1.0991x; 1.0991x over previous
//
#include <hip/hip_runtime.h>
#include <hip/hip_bf16.h>

typedef float f32x4 __attribute__((ext_vector_type(4)));
typedef short s16x8 __attribute__((ext_vector_type(8)));

#define D_DIM 4096
#define N_COLS 384
#define NT 24            // 16-wide col tiles (global)
#define BM 32
#define KITERS 64        // 4096 / 64
#define DSTRIDE 196      // Dmat padded stride (192 + 4)

__device__ __forceinline__ unsigned short f2bf(float f) {
    unsigned u = __float_as_uint(f);
    u += 0x7fffu + ((u >> 16) & 1u);   // RNE
    return (unsigned short)(u >> 16);
}

__global__ __launch_bounds__(64) void reg_init_kernel(const float* __restrict__ C,
                                                      const float* __restrict__ Csin,
                                                      float* __restrict__ reg_out) {
    if (threadIdx.x == 0)
        reg_out[0] = 0.05f * (fabsf(C[0]) + fabsf(C[1]) + fabsf(C[2]) + fabsf(Csin[0]));
}

// Build W [4096 x 384] bf16 in MFMA B-fragment-packed layout:
// element (k, n): chunk = (k>>5)*NT + (n>>4); lane = (((k&31)>>3)<<4) | (n&15); j = k&7
// One wave builds one 1KB chunk. Also accumulates REG_W * sum|U|/size.
__global__ __launch_bounds__(64) void build_w_kernel(const float* __restrict__ U1,
                                                     const float* __restrict__ U2,
                                                     const float* __restrict__ U3,
                                                     unsigned short* __restrict__ W,
                                                     float* __restrict__ reg_out) {
    const int ks = blockIdx.x / NT;
    const int ct = blockIdx.x % NT;
    const int l  = threadIdx.x;
    const int n  = ct * 16 + (l & 15);
    const int kb = ks * 32 + ((l >> 4) << 3);

    const float* src;
    float scale;
    if (n < 64)       { src = U1 + n;                  scale = 0.01f / 262144.f; }
    else if (n < 128) { src = U2 + (n - 64);           scale = 0.01f / 524288.f; }
    else if (n < 192) { src = U2 + 262144 + (n - 128); scale = 0.01f / 524288.f; }
    else if (n < 256) { src = U3 + (n - 192);          scale = 0.01f / 786432.f; }
    else if (n < 320) { src = U3 + 262144 + (n - 256); scale = 0.01f / 786432.f; }
    else              { src = U3 + 524288 + (n - 320); scale = 0.01f / 786432.f; }

    unsigned short h[8];
    float sabs = 0.f;
#pragma unroll
    for (int j = 0; j < 8; ++j) {
        float u = src[(size_t)(kb + j) * 64];
        sabs += fabsf(u);
        h[j] = f2bf(u);
    }
    uint4 pk;
    pk.x = (unsigned)h[0] | ((unsigned)h[1] << 16);
    pk.y = (unsigned)h[2] | ((unsigned)h[3] << 16);
    pk.z = (unsigned)h[4] | ((unsigned)h[5] << 16);
    pk.w = (unsigned)h[6] | ((unsigned)h[7] << 16);
    *(uint4*)(W + ((size_t)blockIdx.x * 64 + l) * 8) = pk;

    sabs *= scale;
#pragma unroll
    for (int off = 32; off >= 1; off >>= 1)
        sabs += __shfl_xor(sabs, off, 64);
    if (l == 0) atomicAdd(reg_out, sabs);
}

// Fused GEMM + sin + nonlinear combine, split into two N-halves per row-block.
// grid = 512: blockIdx = rb*2 + half. half 0: cols 0..191 (t1, t2, sin, beta);
// half 1: cols 192..383 (t3). 512 threads = 8 waves; wave = (rt, 3 col-tiles).
__global__ __launch_bounds__(512) void poly_main_kernel(const float* __restrict__ X,
                                                        const unsigned short* __restrict__ W,
                                                        const float* __restrict__ C,
                                                        const float* __restrict__ beta,
                                                        const float* __restrict__ Csin,
                                                        float* __restrict__ part1,
                                                        float* __restrict__ part2) {
    __shared__ short Atile[2][2][2][512];   // [buf][ks][rt][lane*8] frag-packed, 8 KB
    __shared__ float Dmat[BM][DSTRIDE];     // 24.5 KB (local 192 cols)
    __shared__ float sinrow[BM];

    const int t    = threadIdx.x;
    const int lane = t & 63;
    const int wv   = t >> 6;
    const int rb   = blockIdx.x >> 1;
    const int half = blockIdx.x & 1;
    const int row0 = rb * BM;
    const int rt   = wv >> 2;               // wave's row tile (0..1)
    const int wc   = wv & 3;                // wave's col group (0..3)
    const int ct0  = half * 12 + wc * 3;    // global col-tile base

    // staging assignment: thread -> (row, 4 consecutive k)
    const int srow = t >> 4;                // 0..31
    const int sc4  = (t & 15) << 2;         // 0..60 within BK=64
    const int ks_s = sc4 >> 5;
    const int rt_s = srow >> 4;
    const int lane_a = (((sc4 & 31) >> 3) << 4) | (srow & 15);
    const int j0 = sc4 & 7;

    const float* xp = X + (size_t)(row0 + srow) * D_DIM + sc4;
    short* awr = &Atile[0][ks_s][rt_s][lane_a * 8 + j0];
    const int bufoff = 2 * 2 * 512;

    const s16x8* __restrict__ Wf = (const s16x8*)W;

    f32x4 acc[3];
#pragma unroll
    for (int c = 0; c < 3; ++c) acc[c] = (f32x4){0.f, 0.f, 0.f, 0.f};
    float sinacc = 0.f;

    // prologue: prefetch X iter0 and B iter0
    f32x4 xv = *(const f32x4*)xp;
    s16x8 bcur[2][3], bnxt[2][3];
#pragma unroll
    for (int ks = 0; ks < 2; ++ks)
#pragma unroll
        for (int c = 0; c < 3; ++c)
            bcur[ks][c] = Wf[((size_t)ks * NT + ct0 + c) * 64 + lane];

    for (int it = 0; it < KITERS; ++it) {
        const int itn = (it + 1 < KITERS) ? it + 1 : it;
        // prefetch next X (overlaps this iter's barrier + MFMA)
        f32x4 xn = *(const f32x4*)(xp + (size_t)itn * 64);

        if (half == 0)
            sinacc += __sinf(xv.x) + __sinf(xv.y) + __sinf(xv.z) + __sinf(xv.w);
        short4 hb;
        hb.x = (short)f2bf(xv.x);
        hb.y = (short)f2bf(xv.y);
        hb.z = (short)f2bf(xv.z);
        hb.w = (short)f2bf(xv.w);
        *(short4*)(awr + (it & 1) * bufoff) = hb;
        __syncthreads();

        // prefetch next B fragments (L2-resident, 6 x 16B coalesced)
#pragma unroll
        for (int ks = 0; ks < 2; ++ks)
#pragma unroll
            for (int c = 0; c < 3; ++c)
                bnxt[ks][c] = Wf[((size_t)(itn * 2 + ks) * NT + ct0 + c) * 64 + lane];

        s16x8 a0 = *(const s16x8*)(&Atile[it & 1][0][rt][lane * 8]);
        s16x8 a1 = *(const s16x8*)(&Atile[it & 1][1][rt][lane * 8]);
#pragma unroll
        for (int c = 0; c < 3; ++c) {
            acc[c] = __builtin_amdgcn_mfma_f32_16x16x32_bf16(a0, bcur[0][c], acc[c], 0, 0, 0);
            acc[c] = __builtin_amdgcn_mfma_f32_16x16x32_bf16(a1, bcur[1][c], acc[c], 0, 0, 0);
        }
#pragma unroll
        for (int ks = 0; ks < 2; ++ks)
#pragma unroll
            for (int c = 0; c < 3; ++c)
                bcur[ks][c] = bnxt[ks][c];
        xv = xn;
    }

    // ---- epilogue ----
    const int lr4 = (lane >> 4) << 2;
    const int lc  = lane & 15;
#pragma unroll
    for (int c = 0; c < 3; ++c) {
        const int col = (wc * 3 + c) * 16 + lc;   // local col 0..191
#pragma unroll
        for (int i = 0; i < 4; ++i)
            Dmat[rt * 16 + lr4 + i][col] = acc[c][i];
    }

    if (half == 0) {
#pragma unroll
        for (int off = 1; off < 16; off <<= 1)
            sinacc += __shfl_xor(sinacc, off, 16);
        if ((t & 15) == 0) sinrow[srow] = sinacc;
    }
    __syncthreads();

    const int crow = t >> 4;
    const int cc   = t & 15;
    if (half == 0) {
        float t1 = 0.f, t2 = 0.f;
#pragma unroll
        for (int rr = 0; rr < 64; rr += 16) {
            const int r = rr + cc;
            t1 += Dmat[crow][r];
            t2 += Dmat[crow][64 + r] * Dmat[crow][128 + r];
        }
#pragma unroll
        for (int off = 1; off < 16; off <<= 1) {
            t1 += __shfl_xor(t1, off, 16);
            t2 += __shfl_xor(t2, off, 16);
        }
        if (cc == 0)
            part1[row0 + crow] = beta[0] + C[0] * t1 + C[1] * t2
                               + Csin[0] * sinrow[crow];
    } else {
        float t3 = 0.f;
#pragma unroll
        for (int rr = 0; rr < 64; rr += 16) {
            const int r = rr + cc;
            t3 += Dmat[crow][r] * Dmat[crow][64 + r] * Dmat[crow][128 + r];
        }
#pragma unroll
        for (int off = 1; off < 16; off <<= 1)
            t3 += __shfl_xor(t3, off, 16);
        if (cc == 0)
            part2[row0 + crow] = C[2] * t3;
    }
}

__global__ __launch_bounds__(256) void combine_kernel(const float* __restrict__ p1,
                                                      const float* __restrict__ p2,
                                                      float* __restrict__ out) {
    const int i = blockIdx.x * 256 + threadIdx.x;
    out[i] = p1[i] + p2[i];
}

extern "C" void kernel_launch(void* const* d_in, const int* in_sizes, int n_in,
                              void* d_out, int out_size, void* d_ws, size_t ws_size,
                              hipStream_t stream) {
    const float* X   = (const float*)d_in[0];
    const float* U1  = (const float*)d_in[1];
    const float* U2  = (const float*)d_in[2];
    const float* U3  = (const float*)d_in[3];
    const float* Cc  = (const float*)d_in[4];
    const float* bet = (const float*)d_in[5];
    const float* Cs  = (const float*)d_in[6];
    float* out = (float*)d_out;

    unsigned short* W = (unsigned short*)d_ws;                  // 3 MiB bf16, frag-packed
    float* part1 = (float*)((char*)d_ws + 3u * 1024u * 1024u);  // 32 KiB
    float* part2 = part1 + 8192;                                // 32 KiB

    reg_init_kernel<<<1, 64, 0, stream>>>(Cc, Cs, out + 8192);
    build_w_kernel<<<128 * NT, 64, 0, stream>>>(U1, U2, U3, W, out + 8192);
    poly_main_kernel<<<512, 512, 0, stream>>>(X, W, Cc, bet, Cs, part1, part2);
    combine_kernel<<<32, 256, 0, stream>>>(part1, part2, out);
}